// Round 3
// baseline (146.914 us; speedup 1.0000x reference)
//
#include <hip/hip_runtime.h>

// (B, D, H, W, K) = (64, 256, 32, 32, 512)
#define DIM    256
#define KCODE  512
#define NPOS   1024
#define BATCH  64
#define NPB    128           // positions per block
#define KD     16            // dims per K-step (32x32x16 MFMA)
#define KSTEPS (DIM / KD)    // 16
#define EPS    0.05f
#define ENT    8

using bf16x8 = __attribute__((ext_vector_type(8))) __bf16;
using bf16x4 = __attribute__((ext_vector_type(4))) __bf16;
using f32x16 = __attribute__((ext_vector_type(16))) float;

// workspace layout (bytes)
#define WS_CNT   0
#define WS_ESQ   64
#define WS_WPK   4096
#define WS_LIST  (4096 + 512 * 1024)

// swizzle: XOR byte-bits[5:4] of the 16B slot with row-bits[2:1]
// -> 8 consecutive 64B rows cover all 8 bank-groups bijectively per slot.
#define SWZ(r) ((((r) >> 1) & 3) << 4)

// ---------------- prep: e_sq in fp64 (parallel) + zero refine counter ----------------
__global__ __launch_bounds__(256) void prep_esq(const float* __restrict__ w,
                                                float* __restrict__ esq,
                                                int* __restrict__ cnt) {
    __shared__ double sh[8][32];
    if (blockIdx.x == 0 && threadIdx.x == 0) *cnt = 0;
    const int code = blockIdx.x * 32 + (threadIdx.x & 31);
    const int sl = threadIdx.x >> 5;
    double s = 0.0;
    for (int d = sl * 32; d < sl * 32 + 32; ++d) {
        double v = (double)w[d * KCODE + code];
        s = fma(v, v, s);
    }
    sh[sl][threadIdx.x & 31] = s;
    __syncthreads();
    if (threadIdx.x < 32) {
        double t = 0.0;
        for (int i = 0; i < 8; ++i) t += sh[i][threadIdx.x];
        esq[blockIdx.x * 32 + threadIdx.x] = (float)t;
    }
}

// ---------------- prep: pack w into frag-ready swizzled hi|lo bf16 image ----------------
// row (64B) per (k-step t, code c): [hi d0..7 | hi d8..15 | lo d0..7 | lo d8..15], XOR-swizzled
__global__ __launch_bounds__(256) void prep_wpack(const float* __restrict__ w,
                                                  unsigned char* __restrict__ wpk) {
    int gid = blockIdx.x * 256 + threadIdx.x;   // 16384 = 16t * 2g * 512c
    int c = gid & 511;
    int r = gid >> 9;
    int t = r >> 1, g = r & 1;
    bf16x8 hi, lo;
#pragma unroll
    for (int j = 0; j < 8; ++j) {
        float v = w[(16 * t + 8 * g + j) * KCODE + c];
        __bf16 h = (__bf16)v;
        hi[j] = h;
        lo[j] = (__bf16)(v - (float)h);
    }
    unsigned char* row = wpk + ((size_t)t * KCODE + c) * 64;
    int sw = SWZ(c);
    *(bf16x8*)(row + ((g * 16) ^ sw))        = hi;
    *(bf16x8*)(row + (((2 + g) * 16) ^ sw))  = lo;
}

// ---------------- main: 3-pass split-bf16 MFMA, 2-phase pipelined ----------------
__global__ __launch_bounds__(512, 2) void vq_main(
    const float* __restrict__ x, const unsigned char* __restrict__ wpk,
    const float* __restrict__ esq, const float* __restrict__ w,
    float* __restrict__ quant, float* __restrict__ argm,
    int* __restrict__ cnt, int* __restrict__ list) {

    __shared__ __align__(16) unsigned char At[2][KCODE * 64]; // 64 KB
    __shared__ __align__(16) unsigned char Bt[2][NPB * 64];   // 16 KB
    __shared__ float esq_s[KCODE];
    __shared__ float red1[8][NPB], red2[8][NPB];
    __shared__ int   redi[8][NPB];
    __shared__ float bestv[NPB];
    __shared__ int   idxbuf[NPB];

    const int tid  = threadIdx.x;
    const int wv   = tid >> 6;
    const int lane = tid & 63;
    const int L    = lane & 31;
    const int h5   = lane >> 5;

    const int p0 = blockIdx.x * NPB;
    const int b  = p0 >> 10;
    const int n0 = p0 & (NPOS - 1);

    // B-staging identity (all 512 threads): pos + 4-dim slice q
    const int pos = tid & 127;
    const int q   = tid >> 7;           // 0..3
    const int gq  = q >> 1, o8 = (q & 1) * 8;
    const int swp = SWZ(pos);

    esq_s[tid] = esq[tid];

    f32x16 acc[2][4] = {};

#define STAGE_A(buf, t)                                                           \
    {                                                                             \
        const unsigned char* gA = wpk + (size_t)(t) * (KCODE * 64);               \
        _Pragma("unroll")                                                         \
        for (int r = 0; r < 4; ++r)                                               \
            __builtin_amdgcn_global_load_lds(                                     \
                (const __attribute__((address_space(1))) void*)(gA + r * 8192 + tid * 16), \
                (__attribute__((address_space(3))) void*)(&At[buf][r * 8192 + tid * 16]),  \
                16, 0, 0);                                                        \
    }

#define B_LOAD(t)                                                                 \
    {                                                                             \
        const float* xp = x + ((size_t)b * DIM + (t) * KD + q * 4) * NPOS + n0 + pos; \
        bv0 = xp[0]; bv1 = xp[NPOS]; bv2 = xp[2 * NPOS]; bv3 = xp[3 * NPOS];      \
    }

#define B_WRITE(buf)                                                              \
    {                                                                             \
        __bf16 h0 = (__bf16)bv0, h1 = (__bf16)bv1, h2 = (__bf16)bv2, h3 = (__bf16)bv3; \
        bf16x4 hv = {h0, h1, h2, h3};                                             \
        bf16x4 lv = {(__bf16)(bv0 - (float)h0), (__bf16)(bv1 - (float)h1),        \
                     (__bf16)(bv2 - (float)h2), (__bf16)(bv3 - (float)h3)};       \
        unsigned char* row = &Bt[buf][pos * 64];                                  \
        *(bf16x4*)(row + (((gq) << 4) ^ swp) + o8)       = hv;                    \
        *(bf16x4*)(row + (((2 + gq) << 4) ^ swp) + o8)   = lv;                    \
    }

#define COMPUTE(buf)                                                              \
    {                                                                             \
        bf16x8 ah[2], al[2];                                                      \
        _Pragma("unroll")                                                         \
        for (int fm = 0; fm < 2; ++fm) {                                          \
            int ar = wv * 64 + fm * 32 + L;                                       \
            const unsigned char* rp = &At[buf][ar * 64];                          \
            int sw = SWZ(ar);                                                     \
            ah[fm] = *(const bf16x8*)(rp + ((h5 << 4) ^ sw));                     \
            al[fm] = *(const bf16x8*)(rp + (((2 + h5) << 4) ^ sw));               \
        }                                                                         \
        _Pragma("unroll")                                                         \
        for (int fn = 0; fn < 4; ++fn) {                                          \
            int pr = fn * 32 + L;                                                 \
            const unsigned char* rp = &Bt[buf][pr * 64];                          \
            int sw = SWZ(pr);                                                     \
            bf16x8 bh = *(const bf16x8*)(rp + ((h5 << 4) ^ sw));                  \
            bf16x8 bl = *(const bf16x8*)(rp + (((2 + h5) << 4) ^ sw));            \
            _Pragma("unroll")                                                     \
            for (int fm = 0; fm < 2; ++fm) {                                      \
                acc[fm][fn] = __builtin_amdgcn_mfma_f32_32x32x16_bf16(ah[fm], bh, acc[fm][fn], 0, 0, 0); \
                acc[fm][fn] = __builtin_amdgcn_mfma_f32_32x32x16_bf16(ah[fm], bl, acc[fm][fn], 0, 0, 0); \
                acc[fm][fn] = __builtin_amdgcn_mfma_f32_32x32x16_bf16(al[fm], bh, acc[fm][fn], 0, 0, 0); \
            }                                                                     \
        }                                                                         \
    }

    float bv0, bv1, bv2, bv3;

    // prologue: stage step 0 into buf 0
    B_LOAD(0);
    STAGE_A(0, 0);
    B_WRITE(0);
    asm volatile("s_waitcnt vmcnt(0)" ::: "memory");
    __syncthreads();

    for (int t = 0; t < KSTEPS - 1; ++t) {
        const int c = t & 1;
        B_LOAD(t + 1);          // issue early (T14)
        STAGE_A(c ^ 1, t + 1);  // async DMA, in flight across compute
        COMPUTE(c);
        B_WRITE(c ^ 1);         // write late, just before barrier
        asm volatile("s_waitcnt vmcnt(0)" ::: "memory");
        __syncthreads();
    }
    COMPUTE((KSTEPS - 1) & 1);

    // ---------------- epilogue: score, per-lane top-2, argmin ----------------
    float v1[4] = {3.4e38f, 3.4e38f, 3.4e38f, 3.4e38f};
    float v2[4] = {3.4e38f, 3.4e38f, 3.4e38f, 3.4e38f};
#pragma unroll
    for (int fm = 0; fm < 2; ++fm)
#pragma unroll
        for (int r = 0; r < 16; ++r) {
            int code = wv * 64 + fm * 32 + (r & 3) + 8 * (r >> 2) + 4 * h5;
            float e = esq_s[code];
#pragma unroll
            for (int fn = 0; fn < 4; ++fn) {
                float s = fmaf(-2.f, acc[fm][fn][r], e);
                acc[fm][fn][r] = s;
                float lo_ = fminf(s, v1[fn]);
                float hi_ = fmaxf(s, v1[fn]);
                v1[fn] = lo_;
                v2[fn] = fminf(v2[fn], hi_);
            }
        }
#pragma unroll
    for (int fn = 0; fn < 4; ++fn) {
        float o1 = __shfl_xor(v1[fn], 32, 64);
        float o2 = __shfl_xor(v2[fn], 32, 64);
        float mn = fminf(v1[fn], o1);
        float mx = fmaxf(v1[fn], o1);
        v1[fn] = mn;
        v2[fn] = fminf(fminf(v2[fn], o2), mx);
        if (h5 == 0) { red1[wv][fn * 32 + L] = v1[fn]; red2[wv][fn * 32 + L] = v2[fn]; }
    }
    __syncthreads();
    float gapv = 0.f;
    if (tid < NPB) {
        float g1 = red1[0][tid], g2 = red2[0][tid];
#pragma unroll
        for (int wvi = 1; wvi < 8; ++wvi) {
            float a1 = red1[wvi][tid], a2 = red2[wvi][tid];
            float mn = fminf(g1, a1), mx = fmaxf(g1, a1);
            g1 = mn; g2 = fminf(fminf(g2, a2), mx);
        }
        bestv[tid] = g1;
        gapv = g2 - g1;
    }
    __syncthreads();
    // rescan for argmin index (min code among exact matches)
#pragma unroll
    for (int fn = 0; fn < 4; ++fn) {
        float tgt = bestv[fn * 32 + L];
        int cand = 0x7FFFFFFF;
#pragma unroll
        for (int fm = 0; fm < 2; ++fm)
#pragma unroll
            for (int r = 0; r < 16; ++r) {
                int code = wv * 64 + fm * 32 + (r & 3) + 8 * (r >> 2) + 4 * h5;
                if (acc[fm][fn][r] == tgt) cand = min(cand, code);
            }
        int oc = __shfl_xor(cand, 32, 64);
        cand = min(cand, oc);
        if (h5 == 0) redi[wv][fn * 32 + L] = cand;
    }
    __syncthreads();
    if (tid < NPB) {
        int bi = redi[0][tid];
#pragma unroll
        for (int wvi = 1; wvi < 8; ++wvi) bi = min(bi, redi[wvi][tid]);
        idxbuf[tid] = bi;
        argm[(size_t)b * NPOS + n0 + tid] = (float)bi;
        if (gapv < EPS) {
            int slot = atomicAdd(cnt, 1);
            list[slot] = p0 + tid;
        }
    }
    __syncthreads();
    // quant gather-write, coalesced over positions
    {
        const int dg = q;               // 0..3 -> 64 d-rows each
        const int bi = idxbuf[pos];
        float* qb = quant + ((size_t)b * DIM + dg * 64) * NPOS + n0 + pos;
#pragma unroll 8
        for (int dd = 0; dd < 64; ++dd)
            qb[(size_t)dd * NPOS] = w[(dg * 64 + dd) * KCODE + bi];
    }
}

// ---------------- refine: exact fp64 distances for near-tie positions ----------------
__global__ __launch_bounds__(256) void refine(const float* __restrict__ x,
                                              const float* __restrict__ w,
                                              float* __restrict__ quant,
                                              float* __restrict__ argm,
                                              const int* __restrict__ cnt,
                                              const int* __restrict__ list) {
    __shared__ float xs[ENT][DIM];
    __shared__ double dv[256];
    __shared__ int    di[256];
    const int tid = threadIdx.x;
    const int n = *cnt;
    for (int base = blockIdx.x * ENT; base < n; base += gridDim.x * ENT) {
        int nk = min(ENT, n - base);
        for (int e = 0; e < nk; ++e) {
            int p = list[base + e];
            xs[e][tid] = x[((size_t)(p >> 10) * DIM + tid) * NPOS + (p & (NPOS - 1))];
        }
        __syncthreads();
        double a0[ENT], a1[ENT], sw0 = 0.0, sw1 = 0.0;
#pragma unroll
        for (int e = 0; e < ENT; ++e) { a0[e] = 0.0; a1[e] = 0.0; }
        for (int d = 0; d < DIM; ++d) {
            double w0 = (double)w[d * KCODE + tid];
            double w1 = (double)w[d * KCODE + tid + 256];
            sw0 = fma(w0, w0, sw0);
            sw1 = fma(w1, w1, sw1);
#pragma unroll
            for (int e = 0; e < ENT; ++e) {
                double xv = (double)xs[e][d];
                a0[e] = fma(w0, xv, a0[e]);
                a1[e] = fma(w1, xv, a1[e]);
            }
        }
        for (int e = 0; e < nk; ++e) {
            double d0 = sw0 - 2.0 * a0[e];
            double d1 = sw1 - 2.0 * a1[e];
            double bvv; int bi;
            if (d1 < d0) { bvv = d1; bi = tid + 256; } else { bvv = d0; bi = tid; }
            dv[tid] = bvv; di[tid] = bi;
            __syncthreads();
            for (int off = 128; off > 0; off >>= 1) {
                if (tid < off) {
                    double ov = dv[tid + off]; int oi = di[tid + off];
                    if (ov < dv[tid] || (ov == dv[tid] && oi < di[tid])) { dv[tid] = ov; di[tid] = oi; }
                }
                __syncthreads();
            }
            int p = list[base + e];
            int bsel = di[0];
            size_t pb = (size_t)(p >> 10), pn = (size_t)(p & (NPOS - 1));
            if (tid == 0) argm[pb * NPOS + pn] = (float)bsel;
            quant[(pb * DIM + tid) * NPOS + pn] = w[tid * KCODE + bsel];
            __syncthreads();
        }
        __syncthreads();
    }
}

extern "C" void kernel_launch(void* const* d_in, const int* in_sizes, int n_in,
                              void* d_out, int out_size, void* d_ws, size_t ws_size,
                              hipStream_t stream) {
    (void)in_sizes; (void)n_in; (void)out_size; (void)ws_size;
    const float* x = (const float*)d_in[0];
    const float* w = (const float*)d_in[1];
    float* quant = (float*)d_out;
    float* argm  = quant + (size_t)BATCH * DIM * NPOS;
    char* ws = (char*)d_ws;
    int*   cnt = (int*)(ws + WS_CNT);
    float* esq = (float*)(ws + WS_ESQ);
    unsigned char* wpk = (unsigned char*)(ws + WS_WPK);
    int*   list = (int*)(ws + WS_LIST);

    prep_esq<<<16, 256, 0, stream>>>(w, esq, cnt);
    prep_wpack<<<64, 256, 0, stream>>>(w, wpk);
    vq_main<<<(BATCH * NPOS) / NPB, 512, 0, stream>>>(x, wpk, esq, w, quant, argm, cnt, list);
    refine<<<256, 256, 0, stream>>>(x, w, quant, argm, cnt, list);
}